// Round 3
// baseline (36796.109 us; speedup 1.0000x reference)
//
#include <hip/hip_runtime.h>
#include <math.h>

#define T_STEPS 1024
#define B_SZ    256
#define K_DIM   128
#define IN_DIM  64
#define M_DIM   63
#define NTHREADS 512
#define VW_STRIDE 132   // padded leading dim for Vw in LDS (f32)

__device__ __forceinline__ float fast_sigmoid(float z) {
    return __builtin_amdgcn_rcpf(1.0f + __expf(-z));
}
__device__ __forceinline__ float fast_tanh(float z) {
    z = fminf(15.0f, fmaxf(-15.0f, z));          // v_med3 clamp, avoids inf/inf
    float t = __expf(2.0f * z);
    return (t - 1.0f) * __builtin_amdgcn_rcpf(t + 1.0f);
}

__global__
__attribute__((amdgpu_flat_work_group_size(512, 512)))
__attribute__((amdgpu_waves_per_eu(2, 2)))   // pin allocator target: 2 waves/EU -> 256 VGPR budget
void lstm_fused(const float* __restrict__ x,   // [B,T,IN]
                const float* __restrict__ Wi, const float* __restrict__ Ui,
                const float* __restrict__ Wf, const float* __restrict__ Uf,
                const float* __restrict__ Wg, const float* __restrict__ Ug,
                const float* __restrict__ Wo, const float* __restrict__ Uo,
                const float* __restrict__ Vw, const float* __restrict__ Vb,
                float* __restrict__ out)       // [B,T,M]
{
    __shared__ __align__(16) float hbuf[K_DIM];
    __shared__ __align__(16) float xbuf[2][IN_DIM];
    __shared__ __align__(16) float zact[4 * K_DIM];
    __shared__ __align__(16) float vlds[M_DIM * VW_STRIDE];

    const int b   = blockIdx.x;
    const int tid = threadIdx.x;

    // ---- per-thread weight row: row `tid` of [Wx | Uh], Wx = concat(Wi,Wf,Wg,Wo) ----
    const int rr = tid & 127;
    const float* Wrow;
    const float* Urow;
    if (tid < 128)      { Wrow = Wi + rr * IN_DIM; Urow = Ui + rr * K_DIM; }
    else if (tid < 256) { Wrow = Wf + rr * IN_DIM; Urow = Uf + rr * K_DIM; }
    else if (tid < 384) { Wrow = Wg + rr * IN_DIM; Urow = Ug + rr * K_DIM; }
    else                { Wrow = Wo + rr * IN_DIM; Urow = Uo + rr * K_DIM; }

    float4 wreg[IN_DIM / 4];   // 16 float4 = 64 VGPRs
    float4 ureg[K_DIM / 4];    // 32 float4 = 128 VGPRs
    #pragma unroll
    for (int k = 0; k < IN_DIM / 4; ++k) wreg[k] = ((const float4*)Wrow)[k];
    #pragma unroll
    for (int k = 0; k < K_DIM / 4; ++k) ureg[k] = ((const float4*)Urow)[k];

    // Defeat rematerialization: values become asm-defined, so the allocator
    // must keep them resident instead of re-loading from global each step.
    #pragma unroll
    for (int k = 0; k < IN_DIM / 4; ++k)
        asm volatile("" : "+v"(wreg[k].x), "+v"(wreg[k].y), "+v"(wreg[k].z), "+v"(wreg[k].w));
    #pragma unroll
    for (int k = 0; k < K_DIM / 4; ++k)
        asm volatile("" : "+v"(ureg[k].x), "+v"(ureg[k].y), "+v"(ureg[k].z), "+v"(ureg[k].w));

    // ---- Vw into LDS (padded stride) ----
    for (int idx = tid; idx < M_DIM * K_DIM; idx += NTHREADS) {
        int m = idx >> 7;      // /128
        int k = idx & 127;
        vlds[m * VW_STRIDE + k] = Vw[idx];
    }

    // ---- init state, stage x_0 ----
    if (tid < K_DIM) hbuf[tid] = 0.0f;
    if (tid >= 128 && tid < 128 + IN_DIM)
        xbuf[0][tid - 128] = x[(size_t)b * T_STEPS * IN_DIM + (tid - 128)];
    float c = 0.0f;

    // y-projection role: 8 threads per output column m
    const int ym = tid >> 3;
    const int yj = tid & 7;
    float vbv = 0.0f;
    if (tid < 504 && yj == 0) vbv = Vb[ym];

    __syncthreads();

    const size_t xbase = (size_t)b * T_STEPS * IN_DIM;
    const size_t obase = (size_t)b * T_STEPS * M_DIM;

    for (int t = 0; t < T_STEPS; ++t) {
        const int cur = t & 1, nxt = cur ^ 1;

        // prefetch x_{t+1} into registers (issue early, write after mid barrier)
        float4 xpre;
        if (t + 1 < T_STEPS && tid < 16)
            xpre = ((const float4*)(x + xbase + (size_t)(t + 1) * IN_DIM))[tid];

        // ---- z[tid] = Wx[tid,:]·x_t + Uh[tid,:]·h_{t-1}  (uniform LDS broadcast reads)
        // 4 independent accumulators to break the FMA dependency chain.
        float z0 = 0.f, z1 = 0.f, z2 = 0.f, z3 = 0.f;
        const float4* x4 = (const float4*)xbuf[cur];
        #pragma unroll
        for (int k = 0; k < IN_DIM / 4; k += 4) {
            float4 a0 = x4[k+0], a1 = x4[k+1], a2 = x4[k+2], a3 = x4[k+3];
            z0 += wreg[k+0].x*a0.x + wreg[k+0].y*a0.y + wreg[k+0].z*a0.z + wreg[k+0].w*a0.w;
            z1 += wreg[k+1].x*a1.x + wreg[k+1].y*a1.y + wreg[k+1].z*a1.z + wreg[k+1].w*a1.w;
            z2 += wreg[k+2].x*a2.x + wreg[k+2].y*a2.y + wreg[k+2].z*a2.z + wreg[k+2].w*a2.w;
            z3 += wreg[k+3].x*a3.x + wreg[k+3].y*a3.y + wreg[k+3].z*a3.z + wreg[k+3].w*a3.w;
        }
        const float4* h4 = (const float4*)hbuf;
        #pragma unroll
        for (int k = 0; k < K_DIM / 4; k += 4) {
            float4 a0 = h4[k+0], a1 = h4[k+1], a2 = h4[k+2], a3 = h4[k+3];
            z0 += ureg[k+0].x*a0.x + ureg[k+0].y*a0.y + ureg[k+0].z*a0.z + ureg[k+0].w*a0.w;
            z1 += ureg[k+1].x*a1.x + ureg[k+1].y*a1.y + ureg[k+1].z*a1.z + ureg[k+1].w*a1.w;
            z2 += ureg[k+2].x*a2.x + ureg[k+2].y*a2.y + ureg[k+2].z*a2.z + ureg[k+2].w*a2.w;
            z3 += ureg[k+3].x*a3.x + ureg[k+3].y*a3.y + ureg[k+3].z*a3.z + ureg[k+3].w*a3.w;
        }
        float z = (z0 + z1) + (z2 + z3);

        // ---- deferred y_{t-1} = h_{t-1} @ Vw.T + Vb (reads hbuf before overwrite) ----
        if (t > 0 && tid < 504) {
            const float4* vr = (const float4*)(vlds + ym * VW_STRIDE + yj * 16);
            float p = 0.0f;
            #pragma unroll
            for (int k = 0; k < 4; ++k) {
                float4 v  = vr[k];
                float4 hh = h4[yj * 4 + k];
                p += v.x*hh.x + v.y*hh.y + v.z*hh.z + v.w*hh.w;
            }
            p += __shfl_xor(p, 1);
            p += __shfl_xor(p, 2);
            p += __shfl_xor(p, 4);
            if (yj == 0) out[obase + (size_t)(t - 1) * M_DIM + ym] = p + vbv;
        }

        // ---- gate activation for this thread's z (wave-uniform branch) ----
        float a;
        if (tid >= 256 && tid < 384) a = fast_tanh(z);     // g-gate
        else                         a = fast_sigmoid(z);  // i,f,o
        zact[tid] = a;
        __syncthreads();

        // ---- state update (threads 0..127 own c[k]) ----
        if (tid < K_DIM) {
            float gi = zact[tid];
            float gf = zact[128 + tid];
            float gg = zact[256 + tid];
            float go = zact[384 + tid];
            float tc = fast_tanh(c);      // tanh(c_prev)
            float hn = go * tc;           // h_t = o * tanh(c_prev)   (reference quirk)
            c = gf * c + gi * gg;         // c_t = f*c_prev + i*g
            hbuf[tid] = hn;
        }
        if (t + 1 < T_STEPS && tid < 16)
            ((float4*)xbuf[nxt])[tid] = xpre;
        __syncthreads();
    }

    // ---- final y for t = T-1 ----
    if (tid < 504) {
        const float4* vr = (const float4*)(vlds + ym * VW_STRIDE + yj * 16);
        float p = 0.0f;
        #pragma unroll
        for (int k = 0; k < 4; ++k) {
            float4 v  = vr[k];
            float4 hh = ((const float4*)hbuf)[yj * 4 + k];
            p += v.x*hh.x + v.y*hh.y + v.z*hh.z + v.w*hh.w;
        }
        p += __shfl_xor(p, 1);
        p += __shfl_xor(p, 2);
        p += __shfl_xor(p, 4);
        if (yj == 0) out[obase + (size_t)(T_STEPS - 1) * M_DIM + ym] = p + vbv;
    }
}

extern "C" void kernel_launch(void* const* d_in, const int* in_sizes, int n_in,
                              void* d_out, int out_size, void* d_ws, size_t ws_size,
                              hipStream_t stream) {
    const float* x  = (const float*)d_in[0];
    const float* Wi = (const float*)d_in[1];
    const float* Ui = (const float*)d_in[2];
    const float* Wf = (const float*)d_in[3];
    const float* Uf = (const float*)d_in[4];
    const float* Wg = (const float*)d_in[5];
    const float* Ug = (const float*)d_in[6];
    const float* Wo = (const float*)d_in[7];
    const float* Uo = (const float*)d_in[8];
    const float* Vw = (const float*)d_in[9];
    const float* Vb = (const float*)d_in[10];
    float* out = (float*)d_out;

    lstm_fused<<<dim3(B_SZ), dim3(NTHREADS), 0, stream>>>(
        x, Wi, Ui, Wf, Uf, Wg, Ug, Wo, Uo, Vw, Vb, out);
}

// Round 4
// 3446.363 us; speedup vs baseline: 10.6768x; 10.6768x over previous
//
#include <hip/hip_runtime.h>
#include <math.h>

#define T_STEPS 1024
#define B_SZ    256
#define K_DIM   128
#define IN_DIM  64
#define M_DIM   63
#define NTHREADS 1024
#define VW_STRIDE 132   // padded leading dim for Vw in LDS (f32)

#define DOT4(acc, W, V) (acc) += (W).x*(V).x + (W).y*(V).y + (W).z*(V).z + (W).w*(V).w

__device__ __forceinline__ float fast_sigmoid(float z) {
    return __builtin_amdgcn_rcpf(1.0f + __expf(-z));
}
__device__ __forceinline__ float fast_tanh(float z) {
    z = fminf(15.0f, fmaxf(-15.0f, z));          // med3 clamp, avoids inf/inf
    float t = __expf(2.0f * z);
    return (t - 1.0f) * __builtin_amdgcn_rcpf(t + 1.0f);
}

__global__ __launch_bounds__(NTHREADS)
void lstm_fused(const float* __restrict__ x,   // [B,T,IN]
                const float* __restrict__ Wi, const float* __restrict__ Ui,
                const float* __restrict__ Wf, const float* __restrict__ Uf,
                const float* __restrict__ Wg, const float* __restrict__ Ug,
                const float* __restrict__ Wo, const float* __restrict__ Uo,
                const float* __restrict__ Vw, const float* __restrict__ Vb,
                float* __restrict__ out)       // [B,T,M]
{
    __shared__ __align__(16) float hbuf[K_DIM];
    __shared__ __align__(16) float xbuf[2][IN_DIM];
    __shared__ __align__(16) float zpart[2][512];      // partial dots, per half
    __shared__ __align__(16) float vlds[M_DIM * VW_STRIDE];

    const int b   = blockIdx.x;
    const int tid = threadIdx.x;
    const int r   = tid & 511;      // gate-row 0..511 of [Wx|Uh]
    const int hf  = tid >> 9;       // which half of the 192-wide dot (wave-uniform)

    // ---- weight row pointers: row r of Wx=concat(Wi,Wf,Wg,Wo), Uh=concat(Ui,Uf,Ug,Uo)
    const int rr = r & 127;
    const float* Wrow;
    const float* Urow;
    if (r < 128)      { Wrow = Wi + rr * IN_DIM; Urow = Ui + rr * K_DIM; }
    else if (r < 256) { Wrow = Wf + rr * IN_DIM; Urow = Uf + rr * K_DIM; }
    else if (r < 384) { Wrow = Wg + rr * IN_DIM; Urow = Ug + rr * K_DIM; }
    else              { Wrow = Wo + rr * IN_DIM; Urow = Uo + rr * K_DIM; }

    // Each thread owns 96 of the 192 weights for its row:
    //   hf=0: W[r][0..63] (16 f4) + U[r][0..31] (8 f4)
    //   hf=1: U[r][32..127] (24 f4)
    float4 wreg[24];    // 96 VGPRs
    if (hf == 0) {
        #pragma unroll
        for (int k = 0; k < 16; ++k) wreg[k] = ((const float4*)Wrow)[k];
        #pragma unroll
        for (int k = 0; k < 8;  ++k) wreg[16 + k] = ((const float4*)Urow)[k];
    } else {
        #pragma unroll
        for (int k = 0; k < 24; ++k) wreg[k] = ((const float4*)Urow)[8 + k];
    }
    // Defeat rematerialization (safe now: total demand ~120 < 128 cap).
    #pragma unroll
    for (int k = 0; k < 24; ++k)
        asm volatile("" : "+v"(wreg[k].x), "+v"(wreg[k].y), "+v"(wreg[k].z), "+v"(wreg[k].w));

    // ---- Vw into LDS (padded stride) ----
    for (int idx = tid; idx < M_DIM * K_DIM; idx += NTHREADS) {
        int m = idx >> 7;
        int k = idx & 127;
        vlds[m * VW_STRIDE + k] = Vw[idx];
    }

    const size_t xbase = (size_t)b * T_STEPS * IN_DIM;
    const size_t obase = (size_t)b * T_STEPS * M_DIM;

    // ---- init state, stage x_0 ----
    if (tid < K_DIM) hbuf[tid] = 0.0f;
    if (tid >= 128 && tid < 144)
        ((float4*)xbuf[0])[tid - 128] = ((const float4*)(x + xbase))[tid - 128];
    float c = 0.0f;

    // y-projection role (upper half only): 8 threads per output column m
    const int ym = r >> 3;
    const int yj = r & 7;
    float vbv = 0.0f;
    if (hf == 1 && r < 504 && yj == 0) vbv = Vb[ym];

    __syncthreads();

    for (int t = 0; t < T_STEPS; ++t) {
        const int cur = t & 1, nxt = cur ^ 1;

        // prefetch x_{t+1} (wave 2, lanes 0..15); written to LDS in phase B
        float4 xpre;
        if (t + 1 < T_STEPS && tid >= 128 && tid < 144)
            xpre = ((const float4*)(x + xbase + (size_t)(t + 1) * IN_DIM))[tid - 128];

        // ---- phase A: 96-wide partial dot (wave-uniform LDS broadcast reads) ----
        float z0 = 0.f, z1 = 0.f;
        const float4* h4 = (const float4*)hbuf;
        if (hf == 0) {
            const float4* x4 = (const float4*)xbuf[cur];
            #pragma unroll
            for (int k = 0; k < 16; k += 2) {
                float4 a0 = x4[k], a1 = x4[k + 1];
                DOT4(z0, wreg[k],     a0);
                DOT4(z1, wreg[k + 1], a1);
            }
            #pragma unroll
            for (int k = 0; k < 8; k += 2) {
                float4 a0 = h4[k], a1 = h4[k + 1];
                DOT4(z0, wreg[16 + k], a0);
                DOT4(z1, wreg[17 + k], a1);
            }
        } else {
            #pragma unroll
            for (int k = 0; k < 24; k += 2) {
                float4 a0 = h4[8 + k], a1 = h4[9 + k];
                DOT4(z0, wreg[k],     a0);
                DOT4(z1, wreg[k + 1], a1);
            }
        }
        zpart[hf][r] = z0 + z1;

        // ---- deferred y_{t-1} = h_{t-1} @ Vw.T + Vb (upper half, overlaps phase A) ----
        if (hf == 1 && t > 0 && r < 504) {
            const float4* vr = (const float4*)(vlds + ym * VW_STRIDE + yj * 16);
            float p = 0.0f;
            #pragma unroll
            for (int k = 0; k < 4; ++k) {
                float4 v = vr[k];
                float4 hh = h4[yj * 4 + k];
                DOT4(p, v, hh);
            }
            p += __shfl_xor(p, 1);
            p += __shfl_xor(p, 2);
            p += __shfl_xor(p, 4);
            if (yj == 0) out[obase + (size_t)(t - 1) * M_DIM + ym] = p + vbv;
        }

        __syncthreads();

        // ---- phase B: combine partials, gates, state update (threads 0..127) ----
        if (tid < K_DIM) {
            float zi = zpart[0][tid]       + zpart[1][tid];
            float zf = zpart[0][128 + tid] + zpart[1][128 + tid];
            float zg = zpart[0][256 + tid] + zpart[1][256 + tid];
            float zo = zpart[0][384 + tid] + zpart[1][384 + tid];
            float gi = fast_sigmoid(zi);
            float gf = fast_sigmoid(zf);
            float gg = fast_tanh(zg);
            float go = fast_sigmoid(zo);
            float tc = fast_tanh(c);       // tanh(c_prev)
            hbuf[tid] = go * tc;           // h_t = o * tanh(c_prev)  (reference quirk)
            c = gf * c + gi * gg;          // c_t = f*c_prev + i*g
        }
        if (t + 1 < T_STEPS && tid >= 128 && tid < 144)
            ((float4*)xbuf[nxt])[tid - 128] = xpre;
        __syncthreads();
    }

    // ---- final y for t = T-1 ----
    if (hf == 1 && r < 504) {
        const float4* vr = (const float4*)(vlds + ym * VW_STRIDE + yj * 16);
        const float4* h4 = (const float4*)hbuf;
        float p = 0.0f;
        #pragma unroll
        for (int k = 0; k < 4; ++k) {
            float4 v = vr[k];
            float4 hh = h4[yj * 4 + k];
            DOT4(p, v, hh);
        }
        p += __shfl_xor(p, 1);
        p += __shfl_xor(p, 2);
        p += __shfl_xor(p, 4);
        if (yj == 0) out[obase + (size_t)(T_STEPS - 1) * M_DIM + ym] = p + vbv;
    }
}

extern "C" void kernel_launch(void* const* d_in, const int* in_sizes, int n_in,
                              void* d_out, int out_size, void* d_ws, size_t ws_size,
                              hipStream_t stream) {
    const float* x  = (const float*)d_in[0];
    const float* Wi = (const float*)d_in[1];
    const float* Ui = (const float*)d_in[2];
    const float* Wf = (const float*)d_in[3];
    const float* Uf = (const float*)d_in[4];
    const float* Wg = (const float*)d_in[5];
    const float* Ug = (const float*)d_in[6];
    const float* Wo = (const float*)d_in[7];
    const float* Uo = (const float*)d_in[8];
    const float* Vw = (const float*)d_in[9];
    const float* Vb = (const float*)d_in[10];
    float* out = (float*)d_out;

    lstm_fused<<<dim3(B_SZ), dim3(NTHREADS), 0, stream>>>(
        x, Wi, Ui, Wf, Uf, Wg, Ug, Wo, Uo, Vw, Vb, out);
}